// Round 10
// baseline (342.572 us; speedup 1.0000x reference)
//
#include <hip/hip_runtime.h>
#include <hip/hip_fp16.h>

#define TOKENS 4096
#define NN 2048
#define IN_DIM 1024
#define OUT_DIM 1024
#define TSTEPS 3

typedef _Float16 half8 __attribute__((ext_vector_type(8)));
typedef _Float16 half4 __attribute__((ext_vector_type(4)));
typedef float f32x4 __attribute__((ext_vector_type(4)));
typedef float f32x16 __attribute__((ext_vector_type(16)));

__device__ __forceinline__ void gload_lds16(const void* g, void* l) {
    __builtin_amdgcn_global_load_lds(
        (const __attribute__((address_space(1))) unsigned*)g,
        (__attribute__((address_space(3))) unsigned*)l, 16, 0, 0);
}

#define LGKM(N) asm volatile("s_waitcnt lgkmcnt(" #N ")" ::: "memory")
#define VMCNT(N) asm volatile("s_waitcnt vmcnt(" #N ")" ::: "memory")
#define SCHED0() __builtin_amdgcn_sched_barrier(0)

// ================= pipelined dual GEMM (recurrent step) =================
// Round-8 schedule (counted lgkm/vmcnt ledger, 2 barriers/K-tile, race-clean)
// with 32x32x16 MFMA (2382 TF ceiling vs 1955 for 16x16, 4x fewer MFMA instr).
// 256 blocks x 512 threads (8 waves), tile 256x256, BK=64, wave tile 128x64
// = 4 m-tiles x 2 n-tiles of 32x32, 4 K-subtiles of 16.
__global__ __launch_bounds__(512, 2)
void dual_gemm(const _Float16* __restrict__ A0g, const _Float16* __restrict__ B0g,
               _Float16* __restrict__ C0,
               const _Float16* __restrict__ A1g, const _Float16* __restrict__ B1g,
               _Float16* __restrict__ C1)
{
    __shared__ __align__(16) _Float16 lds[2 * 32768];   // 128 KiB
    const int tid  = threadIdx.x;
    const int wid  = tid >> 6;
    const int lane = tid & 63;

    const int raw  = blockIdx.x;
    const int widx = (raw & 7) * 32 + (raw >> 3);
    const int g    = widx >> 7;
    const int bid  = widx & 127;
    const int by = bid >> 3;
    const int bx = bid & 7;
    const _Float16* __restrict__ A = g ? A1g : A0g;
    const _Float16* __restrict__ B = g ? B1g : B0g;
    _Float16* __restrict__ C = g ? C1 : C0;
    const int brow = by << 8;
    const int bcol = bx << 8;

    const int sr = tid >> 3;
    const int sc = ((tid & 7) ^ (sr & 7)) << 3;
    const _Float16* gA = A + (size_t)(brow + sr) * NN + sc;
    const _Float16* gB = B + (size_t)(bcol + sr) * NN + sc;
    const int ldst = wid << 9;

    auto stA = [&](int T, int h) {
        _Float16* l = lds + (T & 1) * 32768 + h * 8192;
        const _Float16* p = gA + (size_t)(h << 7) * NN + (T << 6);
        gload_lds16(p,           l + ldst);
        gload_lds16(p + 64 * NN, l + 4096 + ldst);
    };
    auto stB = [&](int T, int h) {
        _Float16* l = lds + (T & 1) * 32768 + 16384 + h * 8192;
        const _Float16* p = gB + (size_t)(h << 7) * NN + (T << 6);
        gload_lds16(p,           l + ldst);
        gload_lds16(p + 64 * NN, l + 4096 + ldst);
    };

    // read geometry (32x32x16): frag row = base + (lane&31), k = ks*16 + (lane>>5)*8.
    // LDS f16 idx = row*64 + chunk*8, phys chunk = (ks*2 + (lane>>5)) ^ (row&7);
    // row&7 == lane&7 (all row bases are multiples of 32).
    const int wr = (wid >> 2) << 7;   // 0 / 128
    const int wc = (wid & 3) << 6;    // 0 / 64 / 128 / 192
    const int la31 = lane & 31;
    const int lq2  = lane >> 5;       // 0/1
    const int x7   = lane & 7;
    int cks[4];
#pragma unroll
    for (int ks = 0; ks < 4; ++ks) cks[ks] = (((ks << 1) + lq2) ^ x7) << 3;
    const int aRow = (wr + la31) << 6;             // + m*2048  (m*32 rows)
    const int bRow = 16384 + ((wc + la31) << 6);   // + n*2048

    f32x16 acc[4][2];
#pragma unroll
    for (int m = 0; m < 4; ++m)
#pragma unroll
        for (int n = 0; n < 2; ++n)
#pragma unroll
            for (int j = 0; j < 16; ++j) acc[m][n][j] = 0.f;

    // frag sets: index [i] = (m-offset i>>1, ks-offset i&1) within the group
    half8 af0[4], af1[4], af2[4], af3[4], bf0[4], bf1[4];

    stA(0, 0); stA(0, 1); stB(0, 0); stB(0, 1);
    stA(1, 0); stA(1, 1); stB(1, 0); stB(1, 1);
    VMCNT(8);
    __builtin_amdgcn_s_barrier();
    {   // g0 of tile 0: A m0-1 ks0-1 + B n0-1 ks0-1 (8 reads)
        const _Float16* lb = lds;
#pragma unroll
        for (int i = 0; i < 4; ++i) {
            af0[i] = *(const half8*)&lb[aRow + ((i >> 1) << 11) + cks[i & 1]];
            bf0[i] = *(const half8*)&lb[bRow + ((i >> 1) << 11) + cks[i & 1]];
        }
    }

    for (int T = 0; T < 32; ++T) {
        const _Float16* lb = lds + (T & 1) * 32768;

        // ---- g1 reads: A m2-3 ks0-1 (4) ----
#pragma unroll
        for (int i = 0; i < 4; ++i)
            af1[i] = *(const half8*)&lb[aRow + ((2 + (i >> 1)) << 11) + cks[i & 1]];
        LGKM(4);   // retire g0's 8
        SCHED0();
        __builtin_amdgcn_s_setprio(1);
#pragma unroll
        for (int m = 0; m < 2; ++m)
#pragma unroll
            for (int n = 0; n < 2; ++n)
#pragma unroll
                for (int ks = 0; ks < 2; ++ks)
                    acc[m][n] = __builtin_amdgcn_mfma_f32_32x32x16_f16(af0[m * 2 + ks], bf0[n * 2 + ks], acc[m][n], 0, 0, 0);
        __builtin_amdgcn_s_setprio(0);
        SCHED0();

        // ---- g2 reads: A m0-1 ks2-3 (4) + B n0-1 ks2-3 (4) ----
#pragma unroll
        for (int i = 0; i < 4; ++i) {
            af2[i] = *(const half8*)&lb[aRow + ((i >> 1) << 11) + cks[2 + (i & 1)]];
            bf1[i] = *(const half8*)&lb[bRow + ((i >> 1) << 11) + cks[2 + (i & 1)]];
        }
        LGKM(8);   // retire g1's 4
        SCHED0();
        __builtin_amdgcn_s_setprio(1);
#pragma unroll
        for (int m = 0; m < 2; ++m)
#pragma unroll
            for (int n = 0; n < 2; ++n)
#pragma unroll
                for (int ks = 0; ks < 2; ++ks)
                    acc[m + 2][n] = __builtin_amdgcn_mfma_f32_32x32x16_f16(af1[m * 2 + ks], bf0[n * 2 + ks], acc[m + 2][n], 0, 0, 0);
        __builtin_amdgcn_s_setprio(0);
        SCHED0();

        // ---- g3 reads: A m2-3 ks2-3 (4) ----
#pragma unroll
        for (int i = 0; i < 4; ++i)
            af3[i] = *(const half8*)&lb[aRow + ((2 + (i >> 1)) << 11) + cks[2 + (i & 1)]];
        LGKM(4);   // retire g2's 8
        SCHED0();
        __builtin_amdgcn_s_setprio(1);
#pragma unroll
        for (int m = 0; m < 2; ++m)
#pragma unroll
            for (int n = 0; n < 2; ++n)
#pragma unroll
                for (int ks = 0; ks < 2; ++ks)
                    acc[m][n] = __builtin_amdgcn_mfma_f32_32x32x16_f16(af2[m * 2 + ks], bf1[n * 2 + ks], acc[m][n], 0, 0, 0);
        __builtin_amdgcn_s_setprio(0);
        SCHED0();

        LGKM(0);
        __builtin_amdgcn_s_barrier();          // all waves done reading tile T
        if (T < 30) { stA(T + 2, 0); stA(T + 2, 1); stB(T + 2, 0); stB(T + 2, 1); }
        if (T < 30) { VMCNT(8); }
        else        { VMCNT(0); }
        __builtin_amdgcn_s_barrier();          // tile T+1 resident block-wide
        asm volatile("" ::: "memory");

        // ---- g0 reads of tile T+1; MFMA g3 overlaps ----
        if (T < 31) {
            const _Float16* ln = lds + ((T + 1) & 1) * 32768;
#pragma unroll
            for (int i = 0; i < 4; ++i) {
                af0[i] = *(const half8*)&ln[aRow + ((i >> 1) << 11) + cks[i & 1]];
                bf0[i] = *(const half8*)&ln[bRow + ((i >> 1) << 11) + cks[i & 1]];
            }
        }
        SCHED0();
        __builtin_amdgcn_s_setprio(1);
#pragma unroll
        for (int m = 0; m < 2; ++m)
#pragma unroll
            for (int n = 0; n < 2; ++n)
#pragma unroll
                for (int ks = 0; ks < 2; ++ks)
                    acc[m + 2][n] = __builtin_amdgcn_mfma_f32_32x32x16_f16(af3[m * 2 + ks], bf1[n * 2 + ks], acc[m + 2][n], 0, 0, 0);
        __builtin_amdgcn_s_setprio(0);
        SCHED0();
    }

    // epilogue: 32x32 C/D layout col=lane&31, row=(reg&3)+8*(reg>>2)+4*(lane>>5)
    const int ccol0 = bcol + wc + la31;
#pragma unroll
    for (int m = 0; m < 4; ++m) {
#pragma unroll
        for (int n = 0; n < 2; ++n) {
            const int rb = brow + wr + m * 32 + (lq2 << 2);
#pragma unroll
            for (int j = 0; j < 16; ++j) {
                const int crow = rb + (j & 3) + ((j >> 2) << 3);
                C[(size_t)crow * NN + ccol0 + n * 32] = (_Float16)acc[m][n][j];
            }
        }
    }
}

// ============ pipelined 128x128 GEMM (input/output projections) ============
// EPI 1: v+=bias; oSta=f16(v); oS=f16(tanh(v)).  EPI 2: Cout=v+bias (f32).
template<int EPI>
__global__ __launch_bounds__(256, 2)
void pgemm(const _Float16* __restrict__ A, const _Float16* __restrict__ B,
           float* __restrict__ Cout, const float* __restrict__ bias,
           _Float16* __restrict__ oSta, _Float16* __restrict__ oS,
           int K, int N, int nbxLog2)
{
    __shared__ __align__(16) _Float16 lds[2 * 16384];   // 64 KiB
    const int tid  = threadIdx.x;
    const int wid  = tid >> 6;
    const int lane = tid & 63;

    const int raw  = blockIdx.x;
    const int cpx  = gridDim.x >> 3;
    const int widx = (raw & 7) * cpx + (raw >> 3);
    const int by = widx >> nbxLog2;
    const int bx = widx & ((1 << nbxLog2) - 1);
    const int brow = by << 7;
    const int bcol = bx << 7;

    const int sr = tid >> 3;
    const int sc = ((tid & 7) ^ (sr & 7)) << 3;
    const _Float16* gA = A + (size_t)(brow + sr) * K + sc;
    const _Float16* gB = B + (size_t)(bcol + sr) * K + sc;
    const int ldst = wid << 9;

    auto stA = [&](int T) {
        _Float16* l = lds + (T & 1) * 16384;
        const _Float16* p = gA + (T << 6);
#pragma unroll
        for (int r = 0; r < 4; ++r)
            gload_lds16(p + (size_t)(r * 32) * K, l + r * 2048 + ldst);
    };
    auto stB = [&](int T) {
        _Float16* l = lds + (T & 1) * 16384 + 8192;
        const _Float16* p = gB + (T << 6);
#pragma unroll
        for (int r = 0; r < 4; ++r)
            gload_lds16(p + (size_t)(r * 32) * K, l + r * 2048 + ldst);
    };

    const int wr = (wid >> 1) << 6;
    const int wc = (wid & 1) << 6;
    const int lr = lane & 15;
    const int lq = lane >> 4;
    const int x7 = lr & 7;
    const int c0 = (lq ^ x7) << 3;
    const int c1 = ((4 + lq) ^ x7) << 3;
    const int aRow = (wr + lr) << 6;
    const int bRow = 8192 + ((wc + lr) << 6);

    f32x4 acc[4][4];
#pragma unroll
    for (int m = 0; m < 4; ++m)
#pragma unroll
        for (int n = 0; n < 4; ++n) acc[m][n] = (f32x4){0.f, 0.f, 0.f, 0.f};

    half8 af0[4], af1[4], bf0[4], bf1[4];
    const int NT = K >> 6;

    stA(0); stB(0); stA(1); stB(1);
    VMCNT(8);
    __builtin_amdgcn_s_barrier();
    {
        const _Float16* lb = lds;
#pragma unroll
        for (int m = 0; m < 4; ++m) af0[m] = *(const half8*)&lb[aRow + (m << 10) + c0];
#pragma unroll
        for (int n = 0; n < 4; ++n) bf0[n] = *(const half8*)&lb[bRow + (n << 10) + c0];
    }

    for (int T = 0; T < NT; ++T) {
        const _Float16* lb = lds + (T & 1) * 16384;

#pragma unroll
        for (int m = 0; m < 4; ++m) af1[m] = *(const half8*)&lb[aRow + (m << 10) + c1];
#pragma unroll
        for (int n = 0; n < 4; ++n) bf1[n] = *(const half8*)&lb[bRow + (n << 10) + c1];
        LGKM(8);
        SCHED0();
        __builtin_amdgcn_s_setprio(1);
#pragma unroll
        for (int m = 0; m < 4; ++m)
#pragma unroll
            for (int n = 0; n < 4; ++n)
                acc[m][n] = __builtin_amdgcn_mfma_f32_16x16x32_f16(af0[m], bf0[n], acc[m][n], 0, 0, 0);
        __builtin_amdgcn_s_setprio(0);
        SCHED0();

        LGKM(0);
        __builtin_amdgcn_s_barrier();
        if (T < NT - 2) { stA(T + 2); stB(T + 2); VMCNT(8); }
        else if (T == NT - 2) { VMCNT(0); }
        __builtin_amdgcn_s_barrier();
        asm volatile("" ::: "memory");

        if (T < NT - 1) {
            const _Float16* ln = lds + ((T + 1) & 1) * 16384;
#pragma unroll
            for (int m = 0; m < 4; ++m) af0[m] = *(const half8*)&ln[aRow + (m << 10) + c0];
#pragma unroll
            for (int n = 0; n < 4; ++n) bf0[n] = *(const half8*)&ln[bRow + (n << 10) + c0];
        }
        SCHED0();
        __builtin_amdgcn_s_setprio(1);
#pragma unroll
        for (int m = 0; m < 4; ++m)
#pragma unroll
            for (int n = 0; n < 4; ++n)
                acc[m][n] = __builtin_amdgcn_mfma_f32_16x16x32_f16(af1[m], bf1[n], acc[m][n], 0, 0, 0);
        __builtin_amdgcn_s_setprio(0);
        SCHED0();
    }

    const int cr = lq << 2;
    const int cc = lane & 15;
#pragma unroll
    for (int m = 0; m < 4; ++m) {
#pragma unroll
        for (int n = 0; n < 4; ++n) {
            const int ccol = bcol + wc + n * 16 + cc;
#pragma unroll
            for (int j = 0; j < 4; ++j) {
                const int crow = brow + wr + m * 16 + cr + j;
                float v = acc[m][n][j] + bias[ccol];
                const size_t o = (size_t)crow * N + ccol;
                if (EPI == 1) {
                    oSta[o] = (_Float16)v;
                    oS[o] = (_Float16)tanhf(v);
                } else {
                    Cout[o] = v;
                }
            }
        }
    }
}

// ================= small prep / elementwise kernels =================
__global__ void cvt_f16(const float* __restrict__ in, _Float16* __restrict__ out, int n4) {
    int i = blockIdx.x * blockDim.x + threadIdx.x;
    if (i < n4) {
        f32x4 v = *(const f32x4*)&in[(size_t)i * 4];
        half4 h;
        h[0] = (_Float16)v[0]; h[1] = (_Float16)v[1];
        h[2] = (_Float16)v[2]; h[3] = (_Float16)v[3];
        *(half4*)&out[(size_t)i * 4] = h;
    }
}

__global__ void transmul2(const float* __restrict__ W, const float* __restrict__ J,
                          const float* __restrict__ Mk,
                          _Float16* __restrict__ effT, _Float16* __restrict__ JmT) {
    __shared__ float tw[32][33];
    __shared__ float tj[32][33];
    const int bx = blockIdx.x * 32, by = blockIdx.y * 32;
    const int tx = threadIdx.x, ty0 = threadIdx.y;
#pragma unroll
    for (int r = 0; r < 4; ++r) {
        int ty = ty0 + r * 8;
        size_t idx = (size_t)(by + ty) * NN + bx + tx;
        float mv = Mk[idx];
        tw[ty][tx] = W[idx] * mv;
        tj[ty][tx] = J[idx] * mv;
    }
    __syncthreads();
#pragma unroll
    for (int r = 0; r < 4; ++r) {
        int ty = ty0 + r * 8;
        size_t o = (size_t)(bx + ty) * NN + by + tx;
        effT[o] = (_Float16)tw[tx][ty];
        JmT[o]  = (_Float16)tj[tx][ty];
    }
}

__global__ void tsc_kernel(const float* __restrict__ theta, float* __restrict__ Tsc) {
    int i = blockIdx.x * blockDim.x + threadIdx.x;
    if (i < NN) Tsc[i] = fabsf(sinf(2.0f * theta[i])) * 0.1f;
}

__global__ void step_kernel(const _Float16* __restrict__ signalH, const _Float16* __restrict__ sJH,
                            const float* __restrict__ noise, const float* __restrict__ Tsc,
                            const float* __restrict__ lamp,
                            _Float16* __restrict__ stateH, _Float16* __restrict__ sH) {
    const int i4 = blockIdx.x * blockDim.x + threadIdx.x;
    const float lam = lamp[0];
    const size_t base = (size_t)i4 * 4;
    half4 sg = *(const half4*)&signalH[base];
    half4 dj = *(const half4*)&sJH[base];
    f32x4 nz = *(const f32x4*)&noise[base];
    const int col4 = (int)(base & (NN - 1));
    f32x4 tv = *(const f32x4*)&Tsc[col4];
    half4 so = *(const half4*)&sH[base];
    half4 hs, hn;
#pragma unroll
    for (int j = 0; j < 4; ++j) {
        float s = (float)so[j];
        float arg = (float)sg[j] + lam * ((float)dj[j] * s) + nz[j] * tv[j];
        float st = tanhf(arg);
        hs[j] = (_Float16)st;
        hn[j] = (_Float16)tanhf(st);
    }
    *(half4*)&stateH[base] = hs;
    *(half4*)&sH[base] = hn;
}

extern "C" void kernel_launch(void* const* d_in, const int* in_sizes, int n_in,
                              void* d_out, int out_size, void* d_ws, size_t ws_size,
                              hipStream_t stream) {
    const float* x       = (const float*)d_in[0];
    const float* W_in    = (const float*)d_in[1];
    const float* b_in    = (const float*)d_in[2];
    const float* weights = (const float*)d_in[3];
    const float* Jmat    = (const float*)d_in[4];
    const float* theta   = (const float*)d_in[5];
    const float* lam     = (const float*)d_in[6];
    const float* mask    = (const float*)d_in[7];
    const float* noise   = (const float*)d_in[8];
    const float* W_out   = (const float*)d_in[9];
    const float* b_out   = (const float*)d_in[10];
    float* out = (float*)d_out;

    char* w = (char*)d_ws;
    auto alloc = [&](size_t b) { char* p = w; w += (b + 255) & ~(size_t)255; return p; };
    _Float16* xh      = (_Float16*)alloc((size_t)TOKENS * IN_DIM * 2);
    _Float16* WinH    = (_Float16*)alloc((size_t)NN * IN_DIM * 2);
    _Float16* WoutH   = (_Float16*)alloc((size_t)OUT_DIM * NN * 2);
    _Float16* effT    = (_Float16*)alloc((size_t)NN * NN * 2);
    _Float16* JmT     = (_Float16*)alloc((size_t)NN * NN * 2);
    _Float16* stateH  = (_Float16*)alloc((size_t)TOKENS * NN * 2);
    _Float16* sH      = (_Float16*)alloc((size_t)TOKENS * NN * 2);
    _Float16* signalH = (_Float16*)alloc((size_t)TOKENS * NN * 2);
    _Float16* sJH     = (_Float16*)alloc((size_t)TOKENS * NN * 2);
    float* Tsc        = (float*)alloc((size_t)NN * 4);

    cvt_f16<<<TOKENS * IN_DIM / 4 / 256, 256, 0, stream>>>(x, xh, TOKENS * IN_DIM / 4);
    cvt_f16<<<NN * IN_DIM / 4 / 256, 256, 0, stream>>>(W_in, WinH, NN * IN_DIM / 4);
    cvt_f16<<<OUT_DIM * NN / 4 / 256, 256, 0, stream>>>(W_out, WoutH, OUT_DIM * NN / 4);
    transmul2<<<dim3(NN / 32, NN / 32), dim3(32, 8), 0, stream>>>(weights, Jmat, mask, effT, JmT);
    tsc_kernel<<<NN / 256, 256, 0, stream>>>(theta, Tsc);

    // state = x @ W_in.T + b_in
    pgemm<1><<<(TOKENS / 128) * (NN / 128), 256, 0, stream>>>(
        xh, WinH, nullptr, b_in, stateH, sH, IN_DIM, NN, 4);

    for (int t = 0; t < TSTEPS; ++t) {
        dual_gemm<<<256, 512, 0, stream>>>(stateH, effT, signalH, sH, JmT, sJH);
        step_kernel<<<TOKENS * NN / 4 / 256, 256, 0, stream>>>(
            signalH, sJH, noise + (size_t)t * TOKENS * NN, Tsc, lam, stateH, sH);
    }

    // out = state @ W_out.T + b_out
    pgemm<2><<<(TOKENS / 128) * (OUT_DIM / 128), 256, 0, stream>>>(
        stateH, WoutH, out, b_out, nullptr, nullptr, NN, OUT_DIM, 3);
}

// Round 12
// 339.919 us; speedup vs baseline: 1.0078x; 1.0078x over previous
//
#include <hip/hip_runtime.h>
#include <hip/hip_fp16.h>

#define TOKENS 4096
#define NN 2048
#define IN_DIM 1024
#define OUT_DIM 1024
#define TSTEPS 3

typedef _Float16 half8 __attribute__((ext_vector_type(8)));
typedef _Float16 half4 __attribute__((ext_vector_type(4)));
typedef float f32x4 __attribute__((ext_vector_type(4)));

__device__ __forceinline__ void gload_lds16(const void* g, void* l) {
    __builtin_amdgcn_global_load_lds(
        (const __attribute__((address_space(1))) unsigned*)g,
        (__attribute__((address_space(3))) unsigned*)l, 16, 0, 0);
}

#define LGKM(N) asm volatile("s_waitcnt lgkmcnt(" #N ")" ::: "memory")
#define VMCNT(N) asm volatile("s_waitcnt vmcnt(" #N ")" ::: "memory")
#define SCHED0() __builtin_amdgcn_sched_barrier(0)

// ================= pipelined dual GEMM (recurrent step) =================
// r9 structure (16x16 frags, 0 bank conflicts, race-clean ledger) with
// upfront-24 read issue: all of tile T's ds_reads are issued immediately after
// the residency barrier, consumed by 4 MFMA groups with descending counted
// lgkm waits (15/12/4/0; lgkmcnt field is 4-bit, max 15) so each wave's MFMA
// gates only on its own prefix while the shared LDS queue drains concurrently.
__global__ __launch_bounds__(512, 2)
void dual_gemm(const _Float16* __restrict__ A0g, const _Float16* __restrict__ B0g,
               _Float16* __restrict__ C0,
               const _Float16* __restrict__ A1g, const _Float16* __restrict__ B1g,
               _Float16* __restrict__ C1)
{
    __shared__ __align__(16) _Float16 lds[2 * 32768];   // 128 KiB
    const int tid  = threadIdx.x;
    const int wid  = tid >> 6;
    const int lane = tid & 63;

    const int raw  = blockIdx.x;
    const int widx = (raw & 7) * 32 + (raw >> 3);
    const int g    = widx >> 7;
    const int bid  = widx & 127;
    const int by = bid >> 3;
    const int bx = bid & 7;
    const _Float16* __restrict__ A = g ? A1g : A0g;
    const _Float16* __restrict__ B = g ? B1g : B0g;
    _Float16* __restrict__ C = g ? C1 : C0;
    const int brow = by << 8;
    const int bcol = bx << 8;

    const int sr = tid >> 3;
    const int sc = ((tid & 7) ^ (sr & 7)) << 3;
    const _Float16* gA = A + (size_t)(brow + sr) * NN + sc;
    const _Float16* gB = B + (size_t)(bcol + sr) * NN + sc;
    const int ldst = wid << 9;

    auto stA = [&](int T, int h) {
        _Float16* l = lds + (T & 1) * 32768 + h * 8192;
        const _Float16* p = gA + (size_t)(h << 7) * NN + (T << 6);
        gload_lds16(p,           l + ldst);
        gload_lds16(p + 64 * NN, l + 4096 + ldst);
    };
    auto stB = [&](int T, int h) {
        _Float16* l = lds + (T & 1) * 32768 + 16384 + h * 8192;
        const _Float16* p = gB + (size_t)(h << 7) * NN + (T << 6);
        gload_lds16(p,           l + ldst);
        gload_lds16(p + 64 * NN, l + 4096 + ldst);
    };

    // read geometry (16x16): frag f16 idx = row*64 + (chunk ^ (row&7))*8
    const int wr = (wid >> 2) << 7;   // 0 / 128
    const int wc = (wid & 3) << 6;    // 0 / 64 / 128 / 192
    const int lr = lane & 15;
    const int lq = lane >> 4;
    const int x7 = lr & 7;
    const int c0 = (lq ^ x7) << 3;
    const int c1 = ((4 + lq) ^ x7) << 3;
    const int aRow = (wr + lr) << 6;             // + m*1024
    const int bRow = 16384 + ((wc + lr) << 6);   // + n*1024

    f32x4 acc[8][4];
#pragma unroll
    for (int m = 0; m < 8; ++m)
#pragma unroll
        for (int n = 0; n < 4; ++n) acc[m][n] = (f32x4){0.f, 0.f, 0.f, 0.f};

    // 24 live fragments: A kk0 (8), A kk1 (8), B kk0 (4), B kk1 (4)
    half8 a0[8], a1[8], b0[4], b1[4];

    // prologue: stage tiles 0,1 (16 calls); vmcnt(8) proves tile 0 resident
    stA(0, 0); stA(0, 1); stB(0, 0); stB(0, 1);
    stA(1, 0); stA(1, 1); stB(1, 0); stB(1, 1);
    VMCNT(8);
    __builtin_amdgcn_s_barrier();
    asm volatile("" ::: "memory");

    for (int T = 0; T < 32; ++T) {
        const _Float16* lb = lds + (T & 1) * 32768;

        // ---- issue ALL 24 reads of tile T (ledger: g0=8, g1=4, g2=8, g3=4) ----
#pragma unroll
        for (int m = 0; m < 4; ++m) a0[m] = *(const half8*)&lb[aRow + (m << 10) + c0];
#pragma unroll
        for (int n = 0; n < 4; ++n) b0[n] = *(const half8*)&lb[bRow + (n << 10) + c0];
#pragma unroll
        for (int m = 4; m < 8; ++m) a0[m] = *(const half8*)&lb[aRow + (m << 10) + c0];
#pragma unroll
        for (int m = 0; m < 4; ++m) a1[m] = *(const half8*)&lb[aRow + (m << 10) + c1];
#pragma unroll
        for (int n = 0; n < 4; ++n) b1[n] = *(const half8*)&lb[bRow + (n << 10) + c1];
#pragma unroll
        for (int m = 4; m < 8; ++m) a1[m] = *(const half8*)&lb[aRow + (m << 10) + c1];

        // ---- G0: m0-3 kk0 (needs oldest 8; lgkm max 15) ----
        LGKM(15);
        SCHED0();
        __builtin_amdgcn_s_setprio(1);
#pragma unroll
        for (int m = 0; m < 4; ++m)
#pragma unroll
            for (int n = 0; n < 4; ++n)
                acc[m][n] = __builtin_amdgcn_mfma_f32_16x16x32_f16(a0[m], b0[n], acc[m][n], 0, 0, 0);
        __builtin_amdgcn_s_setprio(0);
        SCHED0();

        // ---- G1: m4-7 kk0 (needs next 4) ----
        LGKM(12);
        SCHED0();
        __builtin_amdgcn_s_setprio(1);
#pragma unroll
        for (int m = 0; m < 4; ++m)
#pragma unroll
            for (int n = 0; n < 4; ++n)
                acc[m + 4][n] = __builtin_amdgcn_mfma_f32_16x16x32_f16(a0[m + 4], b0[n], acc[m + 4][n], 0, 0, 0);
        __builtin_amdgcn_s_setprio(0);
        SCHED0();

        // ---- G2: m0-3 kk1 (needs next 8) ----
        LGKM(4);
        SCHED0();
        __builtin_amdgcn_s_setprio(1);
#pragma unroll
        for (int m = 0; m < 4; ++m)
#pragma unroll
            for (int n = 0; n < 4; ++n)
                acc[m][n] = __builtin_amdgcn_mfma_f32_16x16x32_f16(a1[m], b1[n], acc[m][n], 0, 0, 0);
        __builtin_amdgcn_s_setprio(0);
        SCHED0();

        LGKM(0);   // g3 retired: this wave done reading tile T
        __builtin_amdgcn_s_barrier();          // #1: ALL waves done with tile T
        if (T < 30) { stA(T + 2, 0); stA(T + 2, 1); stB(T + 2, 0); stB(T + 2, 1); }
        if (T < 30) { VMCNT(8); }              // tile T+1 fully resident
        else        { VMCNT(0); }
        __builtin_amdgcn_s_barrier();          // #2: residency visible block-wide
        asm volatile("" ::: "memory");

        // ---- G3: m4-7 kk1 (registers only; overlaps next iteration's issue) ----
        __builtin_amdgcn_s_setprio(1);
#pragma unroll
        for (int m = 0; m < 4; ++m)
#pragma unroll
            for (int n = 0; n < 4; ++n)
                acc[m + 4][n] = __builtin_amdgcn_mfma_f32_16x16x32_f16(a1[m + 4], b1[n], acc[m + 4][n], 0, 0, 0);
        __builtin_amdgcn_s_setprio(0);
        SCHED0();
    }

    // epilogue: C/D layout col=lane&15, row=(lane>>4)*4+j  [m89-verified]
    const int cr = lq << 2;
    const int cc = lane & 15;
#pragma unroll
    for (int m = 0; m < 8; ++m) {
#pragma unroll
        for (int n = 0; n < 4; ++n) {
            const size_t o0 = (size_t)(brow + wr + m * 16 + cr) * NN
                            + (bcol + wc + n * 16 + cc);
#pragma unroll
            for (int j = 0; j < 4; ++j)
                C[o0 + (size_t)j * NN] = (_Float16)acc[m][n][j];
        }
    }
}

// ============ pipelined 128x128 GEMM (input/output projections) ============
// EPI 1: v+=bias; oSta=f16(v); oS=f16(tanh(v)).  EPI 2: Cout=v+bias (f32).
template<int EPI>
__global__ __launch_bounds__(256, 2)
void pgemm(const _Float16* __restrict__ A, const _Float16* __restrict__ B,
           float* __restrict__ Cout, const float* __restrict__ bias,
           _Float16* __restrict__ oSta, _Float16* __restrict__ oS,
           int K, int N, int nbxLog2)
{
    __shared__ __align__(16) _Float16 lds[2 * 16384];   // 64 KiB
    const int tid  = threadIdx.x;
    const int wid  = tid >> 6;
    const int lane = tid & 63;

    const int raw  = blockIdx.x;
    const int cpx  = gridDim.x >> 3;
    const int widx = (raw & 7) * cpx + (raw >> 3);
    const int by = widx >> nbxLog2;
    const int bx = widx & ((1 << nbxLog2) - 1);
    const int brow = by << 7;
    const int bcol = bx << 7;

    const int sr = tid >> 3;
    const int sc = ((tid & 7) ^ (sr & 7)) << 3;
    const _Float16* gA = A + (size_t)(brow + sr) * K + sc;
    const _Float16* gB = B + (size_t)(bcol + sr) * K + sc;
    const int ldst = wid << 9;

    auto stA = [&](int T) {
        _Float16* l = lds + (T & 1) * 16384;
        const _Float16* p = gA + (T << 6);
#pragma unroll
        for (int r = 0; r < 4; ++r)
            gload_lds16(p + (size_t)(r * 32) * K, l + r * 2048 + ldst);
    };
    auto stB = [&](int T) {
        _Float16* l = lds + (T & 1) * 16384 + 8192;
        const _Float16* p = gB + (T << 6);
#pragma unroll
        for (int r = 0; r < 4; ++r)
            gload_lds16(p + (size_t)(r * 32) * K, l + r * 2048 + ldst);
    };

    const int wr = (wid >> 1) << 6;
    const int wc = (wid & 1) << 6;
    const int lr = lane & 15;
    const int lq = lane >> 4;
    const int x7 = lr & 7;
    const int c0 = (lq ^ x7) << 3;
    const int c1 = ((4 + lq) ^ x7) << 3;
    const int aRow = (wr + lr) << 6;
    const int bRow = 8192 + ((wc + lr) << 6);

    f32x4 acc[4][4];
#pragma unroll
    for (int m = 0; m < 4; ++m)
#pragma unroll
        for (int n = 0; n < 4; ++n) acc[m][n] = (f32x4){0.f, 0.f, 0.f, 0.f};

    half8 af0[4], af1[4], bf0[4], bf1[4];
    const int NT = K >> 6;

    stA(0); stB(0); stA(1); stB(1);
    VMCNT(8);
    __builtin_amdgcn_s_barrier();
    {
        const _Float16* lb = lds;
#pragma unroll
        for (int m = 0; m < 4; ++m) af0[m] = *(const half8*)&lb[aRow + (m << 10) + c0];
#pragma unroll
        for (int n = 0; n < 4; ++n) bf0[n] = *(const half8*)&lb[bRow + (n << 10) + c0];
    }

    for (int T = 0; T < NT; ++T) {
        const _Float16* lb = lds + (T & 1) * 16384;

#pragma unroll
        for (int m = 0; m < 4; ++m) af1[m] = *(const half8*)&lb[aRow + (m << 10) + c1];
#pragma unroll
        for (int n = 0; n < 4; ++n) bf1[n] = *(const half8*)&lb[bRow + (n << 10) + c1];
        LGKM(8);
        SCHED0();
        __builtin_amdgcn_s_setprio(1);
#pragma unroll
        for (int m = 0; m < 4; ++m)
#pragma unroll
            for (int n = 0; n < 4; ++n)
                acc[m][n] = __builtin_amdgcn_mfma_f32_16x16x32_f16(af0[m], bf0[n], acc[m][n], 0, 0, 0);
        __builtin_amdgcn_s_setprio(0);
        SCHED0();

        LGKM(0);
        __builtin_amdgcn_s_barrier();
        if (T < NT - 2) { stA(T + 2); stB(T + 2); VMCNT(8); }
        else if (T == NT - 2) { VMCNT(0); }
        __builtin_amdgcn_s_barrier();
        asm volatile("" ::: "memory");

        if (T < NT - 1) {
            const _Float16* ln = lds + ((T + 1) & 1) * 16384;
#pragma unroll
            for (int m = 0; m < 4; ++m) af0[m] = *(const half8*)&ln[aRow + (m << 10) + c0];
#pragma unroll
            for (int n = 0; n < 4; ++n) bf0[n] = *(const half8*)&ln[bRow + (n << 10) + c0];
        }
        SCHED0();
        __builtin_amdgcn_s_setprio(1);
#pragma unroll
        for (int m = 0; m < 4; ++m)
#pragma unroll
            for (int n = 0; n < 4; ++n)
                acc[m][n] = __builtin_amdgcn_mfma_f32_16x16x32_f16(af1[m], bf1[n], acc[m][n], 0, 0, 0);
        __builtin_amdgcn_s_setprio(0);
        SCHED0();
    }

    const int cr = lq << 2;
    const int cc = lane & 15;
#pragma unroll
    for (int m = 0; m < 4; ++m) {
#pragma unroll
        for (int n = 0; n < 4; ++n) {
            const int ccol = bcol + wc + n * 16 + cc;
#pragma unroll
            for (int j = 0; j < 4; ++j) {
                const int crow = brow + wr + m * 16 + cr + j;
                float v = acc[m][n][j] + bias[ccol];
                const size_t o = (size_t)crow * N + ccol;
                if (EPI == 1) {
                    oSta[o] = (_Float16)v;
                    oS[o] = (_Float16)tanhf(v);
                } else {
                    Cout[o] = v;
                }
            }
        }
    }
}

// ================= small prep / elementwise kernels =================
// one launch casts x, W_in, W_out to f16
__global__ void cvt3(const float* __restrict__ s0, _Float16* __restrict__ d0, int n0,
                     const float* __restrict__ s1, _Float16* __restrict__ d1, int n1,
                     const float* __restrict__ s2, _Float16* __restrict__ d2) {
    int i = blockIdx.x * blockDim.x + threadIdx.x;
    const float* src; _Float16* dst; int k;
    if (i < n0)            { src = s0; dst = d0; k = i; }
    else if (i < n0 + n1)  { src = s1; dst = d1; k = i - n0; }
    else                   { src = s2; dst = d2; k = i - n0 - n1; }
    f32x4 v = *(const f32x4*)&src[(size_t)k * 4];
    half4 h;
    h[0] = (_Float16)v[0]; h[1] = (_Float16)v[1];
    h[2] = (_Float16)v[2]; h[3] = (_Float16)v[3];
    *(half4*)&dst[(size_t)k * 4] = h;
}

__global__ void transmul2(const float* __restrict__ W, const float* __restrict__ J,
                          const float* __restrict__ Mk,
                          _Float16* __restrict__ effT, _Float16* __restrict__ JmT) {
    __shared__ float tw[32][33];
    __shared__ float tj[32][33];
    const int bx = blockIdx.x * 32, by = blockIdx.y * 32;
    const int tx = threadIdx.x, ty0 = threadIdx.y;
#pragma unroll
    for (int r = 0; r < 4; ++r) {
        int ty = ty0 + r * 8;
        size_t idx = (size_t)(by + ty) * NN + bx + tx;
        float mv = Mk[idx];
        tw[ty][tx] = W[idx] * mv;
        tj[ty][tx] = J[idx] * mv;
    }
    __syncthreads();
#pragma unroll
    for (int r = 0; r < 4; ++r) {
        int ty = ty0 + r * 8;
        size_t o = (size_t)(bx + ty) * NN + by + tx;
        effT[o] = (_Float16)tw[tx][ty];
        JmT[o]  = (_Float16)tj[tx][ty];
    }
}

__global__ void tsc_kernel(const float* __restrict__ theta, float* __restrict__ Tsc) {
    int i = blockIdx.x * blockDim.x + threadIdx.x;
    if (i < NN) Tsc[i] = fabsf(sinf(2.0f * theta[i])) * 0.1f;
}

__global__ void step_kernel(const _Float16* __restrict__ signalH, const _Float16* __restrict__ sJH,
                            const float* __restrict__ noise, const float* __restrict__ Tsc,
                            const float* __restrict__ lamp,
                            _Float16* __restrict__ stateH, _Float16* __restrict__ sH) {
    const int i4 = blockIdx.x * blockDim.x + threadIdx.x;
    const float lam = lamp[0];
    const size_t base = (size_t)i4 * 4;
    half4 sg = *(const half4*)&signalH[base];
    half4 dj = *(const half4*)&sJH[base];
    f32x4 nz = *(const f32x4*)&noise[base];
    const int col4 = (int)(base & (NN - 1));
    f32x4 tv = *(const f32x4*)&Tsc[col4];
    half4 so = *(const half4*)&sH[base];
    half4 hs, hn;
#pragma unroll
    for (int j = 0; j < 4; ++j) {
        float s = (float)so[j];
        float arg = (float)sg[j] + lam * ((float)dj[j] * s) + nz[j] * tv[j];
        float st = tanhf(arg);
        hs[j] = (_Float16)st;
        hn[j] = (_Float16)tanhf(st);
    }
    *(half4*)&stateH[base] = hs;
    *(half4*)&sH[base] = hn;
}

extern "C" void kernel_launch(void* const* d_in, const int* in_sizes, int n_in,
                              void* d_out, int out_size, void* d_ws, size_t ws_size,
                              hipStream_t stream) {
    const float* x       = (const float*)d_in[0];
    const float* W_in    = (const float*)d_in[1];
    const float* b_in    = (const float*)d_in[2];
    const float* weights = (const float*)d_in[3];
    const float* Jmat    = (const float*)d_in[4];
    const float* theta   = (const float*)d_in[5];
    const float* lam     = (const float*)d_in[6];
    const float* mask    = (const float*)d_in[7];
    const float* noise   = (const float*)d_in[8];
    const float* W_out   = (const float*)d_in[9];
    const float* b_out   = (const float*)d_in[10];
    float* out = (float*)d_out;

    char* w = (char*)d_ws;
    auto alloc = [&](size_t b) { char* p = w; w += (b + 255) & ~(size_t)255; return p; };
    _Float16* xh      = (_Float16*)alloc((size_t)TOKENS * IN_DIM * 2);
    _Float16* WinH    = (_Float16*)alloc((size_t)NN * IN_DIM * 2);
    _Float16* WoutH   = (_Float16*)alloc((size_t)OUT_DIM * NN * 2);
    _Float16* effT    = (_Float16*)alloc((size_t)NN * NN * 2);
    _Float16* JmT     = (_Float16*)alloc((size_t)NN * NN * 2);
    _Float16* stateH  = (_Float16*)alloc((size_t)TOKENS * NN * 2);
    _Float16* sH      = (_Float16*)alloc((size_t)TOKENS * NN * 2);
    _Float16* signalH = (_Float16*)alloc((size_t)TOKENS * NN * 2);
    _Float16* sJH     = (_Float16*)alloc((size_t)TOKENS * NN * 2);
    float* Tsc        = (float*)alloc((size_t)NN * 4);

    const int n0 = TOKENS * IN_DIM / 4;
    const int n1 = NN * IN_DIM / 4;
    const int n2 = OUT_DIM * NN / 4;
    cvt3<<<(n0 + n1 + n2) / 256, 256, 0, stream>>>(x, xh, n0, W_in, WinH, n1, W_out, WoutH);
    transmul2<<<dim3(NN / 32, NN / 32), dim3(32, 8), 0, stream>>>(weights, Jmat, mask, effT, JmT);
    tsc_kernel<<<NN / 256, 256, 0, stream>>>(theta, Tsc);

    // state = x @ W_in.T + b_in
    pgemm<1><<<(TOKENS / 128) * (NN / 128), 256, 0, stream>>>(
        xh, WinH, nullptr, b_in, stateH, sH, IN_DIM, NN, 4);

    for (int t = 0; t < TSTEPS; ++t) {
        dual_gemm<<<256, 512, 0, stream>>>(stateH, effT, signalH, sH, JmT, sJH);
        step_kernel<<<TOKENS * NN / 4 / 256, 256, 0, stream>>>(
            signalH, sJH, noise + (size_t)t * TOKENS * NN, Tsc, lam, stateH, sH);
    }

    // out = state @ W_out.T + b_out
    pgemm<2><<<(TOKENS / 128) * (OUT_DIM / 128), 256, 0, stream>>>(
        stateH, WoutH, out, b_out, nullptr, nullptr, NN, OUT_DIM, 3);
}